// Round 11
// baseline (156.950 us; speedup 1.0000x reference)
//
#include <hip/hip_runtime.h>

#define B_DIM 2
#define H_DIM 16
#define S_DIM 2048
#define D_DIM 64

constexpr int KB = 64;             // keys per tile
constexpr int NT = S_DIM / KB;     // 32 key tiles
constexpr float CL2E = 0.18033688011112042f;  // (1/sqrt(64)) * log2(e)

typedef __attribute__((ext_vector_type(8))) short short8;   // 8 bf16
typedef __attribute__((ext_vector_type(4))) float f32x4;
typedef __attribute__((ext_vector_type(2))) unsigned uint2v;

__device__ __forceinline__ unsigned pkbf(float lo, float hi) {
  unsigned r;
  asm("v_cvt_pk_bf16_f32 %0, %1, %2" : "=v"(r) : "v"(lo), "v"(hi));
  return r;
}

__device__ __forceinline__ float fexp2(float x) {
  float r;
  asm("v_exp_f32 %0, %1" : "=v"(r) : "v"(x));
  return r;
}

// drain LDS ops (cross-wave visibility) but NOT vmcnt — prefetch global
// loads stay in flight across the barrier (T14).
__device__ __forceinline__ void barrier_lds() {
  asm volatile("s_waitcnt lgkmcnt(0)" ::: "memory");
  __builtin_amdgcn_s_barrier();
  asm volatile("" ::: "memory");
}

// One block = 512 threads (8 waves) = one 256-row q-super-tile: X = rows
// [0,128), Y = rows [128,256); each wave owns 16 rows of X and 16 of Y.
// Phase A: pass1(X) + pass1(Y) fused per K-tile (store-free phase carries
// the doubled compute).  Phase B: pass2(X) + stores.  Phase C: pass2(Y) +
// stores.  Store phases run the minimal recompute pipeline.
__global__ __launch_bounds__(512, 2)
void sdpa_kernel(const float* __restrict__ Qp, const float* __restrict__ Kp,
                 const float* __restrict__ Vp, const int* __restrict__ maskp,
                 float* __restrict__ ctx, float* __restrict__ attn)
{
  __shared__ __align__(16) unsigned short sK[2][KB * 64];   // [buf][key][d] bf16, swizzled, col-masked
  __shared__ __align__(16) unsigned short sV[2][64 * KB];   // [buf][d][key] bf16, swizzled
  __shared__ __align__(16) unsigned short sP[8][16 * 64];   // per-wave P [q16][key] bf16, swizzled

  const int tid  = threadIdx.x;
  const int wave = tid >> 6;
  const int lane = tid & 63;
  const int c = lane & 15;      // fragment col (q within 16)
  const int g = lane >> 4;      // fragment key-subgroup

  // XCD-aware bijective swizzle (256 % 8 == 0)
  const int bid = (blockIdx.x & 7) * 32 + (blockIdx.x >> 3);
  const int bh = bid >> 3;            // 8 super-tiles per (b,h)
  const int qt = bid & 7;
  const int q0x = qt * 256 + wave * 16;
  const int q0y = q0x + 128;
  const size_t bhS = (size_t)bh * S_DIM;

  // staging coords (512 threads)
  const int keyk = tid >> 3;              // K: 0..63
  const int dqk  = (tid & 7) << 3;        // K: d octet 0..56
  const int kpv  = (tid & 31) << 1;       // V: even key 0..62
  const int d4   = (tid >> 5) << 2;       // V: d quad 0..60

  // ---- Q fragments (B-operand): col=q=lane&15, k = kk*32 + g*8 + j ----
  short8 qfX[2], qfY[2];
  #pragma unroll
  for (int kk = 0; kk < 2; ++kk) {
    const float* sx = Qp + (bhS + (size_t)(q0x + c)) * D_DIM + kk*32 + g*8;
    float4 a = ((const float4*)sx)[0];
    float4 b = ((const float4*)sx)[1];
    union { unsigned u[4]; short8 s; } w;
    w.u[0] = pkbf(a.x, a.y); w.u[1] = pkbf(a.z, a.w);
    w.u[2] = pkbf(b.x, b.y); w.u[3] = pkbf(b.z, b.w);
    qfX[kk] = w.s;
    const float* sy = Qp + (bhS + (size_t)(q0y + c)) * D_DIM + kk*32 + g*8;
    float4 ay = ((const float4*)sy)[0];
    float4 by = ((const float4*)sy)[1];
    w.u[0] = pkbf(ay.x, ay.y); w.u[1] = pkbf(ay.z, ay.w);
    w.u[2] = pkbf(by.x, by.y); w.u[3] = pkbf(by.z, by.w);
    qfY[kk] = w.s;
  }

  const float rvSX = maskp[bhS + q0x + c] ? CL2E : 0.0f;
  const float rvSY = maskp[bhS + q0y + c] ? CL2E : 0.0f;

  // prefetch registers
  float4 kA, kB;            // K: 8 floats
  float4 vA, vB;            // V: 2 keys x 4 d
  unsigned kmr;

  auto load_k = [&](int kt_) {
    const float* s = Kp + (bhS + (size_t)(kt_ * KB + keyk)) * D_DIM + dqk;
    kA = ((const float4*)s)[0]; kB = ((const float4*)s)[1];
    kmr = maskp[bhS + kt_ * KB + keyk] ? 0xFFFFFFFFu : 0u;
  };
  auto load_v = [&](int kt_) {
    const float* s0 = Vp + (bhS + (size_t)(kt_ * KB + kpv)) * D_DIM + d4;
    vA = *(const float4*)s0;
    vB = *(const float4*)(s0 + D_DIM);
  };
  // col-masked K staging: masked key rows stored as exact zeros -> sacc==0
  // -> p = exp2(0 + Lm) = 1/sum, exactly the reference's value.
  auto write_k = [&](int buf) {
    union { unsigned u[4]; short8 s; } w;
    w.u[0] = pkbf(kA.x, kA.y) & kmr; w.u[1] = pkbf(kA.z, kA.w) & kmr;
    w.u[2] = pkbf(kB.x, kB.y) & kmr; w.u[3] = pkbf(kB.z, kB.w) & kmr;
    *(short8*)&sK[buf][keyk * 64 + (dqk ^ ((keyk & 7) << 3))] = w.s;
  };
  auto write_v = [&](int buf) {
    float fa[4], fb[4];
    *(float4*)fa = vA; *(float4*)fb = vB;
    #pragma unroll
    for (int e = 0; e < 4; ++e) {
      const int d = d4 + e;
      *(unsigned*)&sV[buf][d * KB + (kpv ^ ((d & 7) << 3))] = pkbf(fa[e], fb[e]);
    }
  };

  unsigned short* const myP = sP[wave];
  const int rh  = lane >> 4;
  const int c16 = lane & 15;
  float* const abx = attn + (bhS + (size_t)q0x) * S_DIM;
  float* const aby = attn + (bhS + (size_t)q0y) * S_DIM;

  // attn copy-out from sP: 4 rows x 256B = 1KB contiguous per store
  auto copyout = [&](float* ab, int kt_) {
    float* const at = ab + kt_*KB;
    #pragma unroll
    for (int j = 0; j < 4; ++j) {
      const int rr = j*4 + rh;
      const int p8 = (c16 >> 1) ^ (rr & 7);
      uint2v u = *(const uint2v*)&myP[rr*64 + p8*8 + (c16 & 1)*4];
      union { unsigned iu; float f; } t0, t1, t2, t3;
      t0.iu = u.x << 16; t1.iu = u.x & 0xFFFF0000u;
      t2.iu = u.y << 16; t3.iu = u.y & 0xFFFF0000u;
      f32x4 o; o[0] = t0.f; o[1] = t1.f; o[2] = t2.f; o[3] = t3.f;
      __builtin_nontemporal_store(o, (f32x4*)(at + (size_t)rr * S_DIM + c16*4));
    }
  };

  auto read_kf = [&](int cur, short8 (&kf)[4][2]) {
    #pragma unroll
    for (int n = 0; n < 4; ++n) {
      const int k2 = n*16 + c;
      const int sw = (c & 7) << 3;
      #pragma unroll
      for (int kk = 0; kk < 2; ++kk)
        kf[n][kk] = *(const short8*)&sK[cur][k2*64 + ((kk*32 + g*8) ^ sw)];
    }
  };

  // ================= phase A: pass1(X) + pass1(Y) =================
  float lsumX = 0.0f, lsumY = 0.0f;
  load_k(0);
  for (int kt = 0; kt < NT; ++kt) {
    const int cur = kt & 1;
    write_k(cur);
    if (kt + 1 < NT) load_k(kt + 1);
    else { load_k(0); load_v(0); }       // prefetch for phase B
    barrier_lds();

    short8 kf[4][2];
    read_kf(cur, kf);
    f32x4 saccX[4], saccY[4];
    #pragma unroll
    for (int n = 0; n < 4; ++n) { saccX[n] = 0.0f; saccY[n] = 0.0f; }
    __builtin_amdgcn_s_setprio(1);
    #pragma unroll
    for (int n = 0; n < 4; ++n)
      #pragma unroll
      for (int kk = 0; kk < 2; ++kk) {
        saccX[n] = __builtin_amdgcn_mfma_f32_16x16x32_bf16(kf[n][kk], qfX[kk], saccX[n], 0, 0, 0);
        saccY[n] = __builtin_amdgcn_mfma_f32_16x16x32_bf16(kf[n][kk], qfY[kk], saccY[n], 0, 0, 0);
      }
    __builtin_amdgcn_s_setprio(0);
    #pragma unroll
    for (int n = 0; n < 4; ++n)
      #pragma unroll
      for (int e = 0; e < 4; ++e) {
        lsumX += fexp2(saccX[n][e] * rvSX);
        lsumY += fexp2(saccY[n][e] * rvSY);
      }
  }
  float LmX, LmY;
  {
    float v = lsumX;
    v += __shfl_xor(v, 16);
    v += __shfl_xor(v, 32);
    LmX = -__log2f(v);
    float u = lsumY;
    u += __shfl_xor(u, 16);
    u += __shfl_xor(u, 32);
    LmY = -__log2f(u);
  }

  // ================= phase B/C: lean pass2 (+ stores) =================
  auto pass2 = [&](const short8 (&qf)[2], float rvS, float Lm, float* ab,
                   f32x4 (&oacc)[4], bool prefetch_next_phase) {
    for (int kt = 0; kt < NT; ++kt) {
      const int cur = kt & 1;
      write_k(cur);
      write_v(cur);
      if (kt + 1 < NT) { load_k(kt + 1); load_v(kt + 1); }
      else if (prefetch_next_phase) { load_k(0); load_v(0); }
      barrier_lds();

      short8 kf[4][2];
      read_kf(cur, kf);
      f32x4 sacc[4];
      #pragma unroll
      for (int n = 0; n < 4; ++n) sacc[n] = 0.0f;
      __builtin_amdgcn_s_setprio(1);
      #pragma unroll
      for (int n = 0; n < 4; ++n)
        #pragma unroll
        for (int kk = 0; kk < 2; ++kk)
          sacc[n] = __builtin_amdgcn_mfma_f32_16x16x32_bf16(kf[n][kk], qf[kk], sacc[n], 0, 0, 0);
      __builtin_amdgcn_s_setprio(0);

      // p = exp2(s*rvS + Lm) -> bf16 into wave-private sP (swizzled)
      #pragma unroll
      for (int n = 0; n < 4; ++n) {
        f32x4 pv;
        #pragma unroll
        for (int e = 0; e < 4; ++e)
          pv[e] = fexp2(__builtin_fmaf(sacc[n][e], rvS, Lm));
        const int swk = (n*16 + g*4) ^ ((c & 7) << 3);
        uint2v pr; pr.x = pkbf(pv[0], pv[1]); pr.y = pkbf(pv[2], pv[3]);
        *(uint2v*)&myP[c*64 + swk] = pr;
      }

      // PV: A = P[q][key] from sP, B = V[key][d] from transposed sV
      short8 pf[2];
      #pragma unroll
      for (int kk = 0; kk < 2; ++kk)
        pf[kk] = *(const short8*)&myP[c*64 + ((kk*32 + g*8) ^ ((c & 7) << 3))];
      __builtin_amdgcn_s_setprio(1);
      #pragma unroll
      for (int n = 0; n < 4; ++n) {
        const int d = n*16 + c;
        const int sw = (d & 7) << 3;
        #pragma unroll
        for (int kk = 0; kk < 2; ++kk) {
          short8 vf = *(const short8*)&sV[cur][d*KB + ((kk*32 + g*8) ^ sw)];
          oacc[n] = __builtin_amdgcn_mfma_f32_16x16x32_bf16(pf[kk], vf, oacc[n], 0, 0, 0);
        }
      }
      __builtin_amdgcn_s_setprio(0);

      copyout(ab, kt);
    }
  };

  f32x4 oaccX[4];
  #pragma unroll
  for (int n = 0; n < 4; ++n) oaccX[n] = 0.0f;
  pass2(qfX, rvSX, LmX, abx, oaccX, true);

  // ctx(X)
  #pragma unroll
  for (int n = 0; n < 4; ++n)
    #pragma unroll
    for (int e = 0; e < 4; ++e)
      ctx[(bhS + (size_t)(q0x + g*4 + e)) * D_DIM + (size_t)(n*16 + c)] = oaccX[n][e];

  f32x4 oaccY[4];
  #pragma unroll
  for (int n = 0; n < 4; ++n) oaccY[n] = 0.0f;
  pass2(qfY, rvSY, LmY, aby, oaccY, false);

  // ctx(Y)
  #pragma unroll
  for (int n = 0; n < 4; ++n)
    #pragma unroll
    for (int e = 0; e < 4; ++e)
      ctx[(bhS + (size_t)(q0y + g*4 + e)) * D_DIM + (size_t)(n*16 + c)] = oaccY[n][e];
}

extern "C" void kernel_launch(void* const* d_in, const int* in_sizes, int n_in,
                              void* d_out, int out_size, void* d_ws, size_t ws_size,
                              hipStream_t stream) {
  const float* Q = (const float*)d_in[0];
  const float* K = (const float*)d_in[1];
  const float* V = (const float*)d_in[2];
  const int*   M = (const int*)d_in[3];
  float* ctx  = (float*)d_out;
  float* attn = ctx + (size_t)B_DIM * H_DIM * S_DIM * D_DIM;
  dim3 grid(B_DIM * H_DIM * (S_DIM / 256));   // 256 blocks of 512 threads
  sdpa_kernel<<<grid, 512, 0, stream>>>(Q, K, V, M, ctx, attn);
}

// Round 12
// 155.323 us; speedup vs baseline: 1.0105x; 1.0105x over previous
//
#include <hip/hip_runtime.h>

#define B_DIM 2
#define H_DIM 16
#define S_DIM 2048
#define D_DIM 64

constexpr int KB = 64;             // keys per tile
constexpr int NT = S_DIM / KB;     // 32 key tiles
constexpr float CL2E = 0.18033688011112042f;  // (1/sqrt(64)) * log2(e)

typedef __attribute__((ext_vector_type(8))) short short8;   // 8 bf16
typedef __attribute__((ext_vector_type(4))) float f32x4;
typedef __attribute__((ext_vector_type(2))) unsigned uint2v;

__device__ __forceinline__ unsigned pkbf(float lo, float hi) {
  unsigned r;
  asm("v_cvt_pk_bf16_f32 %0, %1, %2" : "=v"(r) : "v"(lo), "v"(hi));
  return r;
}

__device__ __forceinline__ float fexp2(float x) {
  float r;
  asm("v_exp_f32 %0, %1" : "=v"(r) : "v"(x));
  return r;
}

// drain LDS ops (cross-wave visibility) but NOT vmcnt — prefetch global
// loads stay in flight across the barrier (T14).
__device__ __forceinline__ void barrier_lds() {
  asm volatile("s_waitcnt lgkmcnt(0)" ::: "memory");
  __builtin_amdgcn_s_barrier();
  asm volatile("" ::: "memory");
}

// One block = 256 threads (4 waves) = one 128-row q-super-tile: X = rows
// [0,64), Y = rows [64,128); each wave owns 16 rows of X and 16 of Y.
// Phase A: pass1(X) (store-free, minimal).  Phase B: pass2(X) || pass1(Y)
// + stores (store-bound; extra compute ~free).  Phase C: pass2(Y) + stores.
// grid=512 -> 2 independent blocks/CU: one block's phase A overlaps the
// other block's store phases (cross-block desync keeps stores draining).
__global__ __launch_bounds__(256, 2)
void sdpa_kernel(const float* __restrict__ Qp, const float* __restrict__ Kp,
                 const float* __restrict__ Vp, const int* __restrict__ maskp,
                 float* __restrict__ ctx, float* __restrict__ attn)
{
  __shared__ __align__(16) unsigned short sK[2][KB * 64];   // [buf][key][d] bf16, swizzled, col-masked
  __shared__ __align__(16) unsigned short sV[2][64 * KB];   // [buf][d][key] bf16, swizzled
  __shared__ __align__(16) unsigned short sP[4][16 * 64];   // per-wave P [q16][key] bf16, swizzled

  const int tid  = threadIdx.x;
  const int wave = tid >> 6;
  const int lane = tid & 63;
  const int c = lane & 15;      // fragment col (q within 16)
  const int g = lane >> 4;      // fragment key-subgroup

  // XCD-aware bijective swizzle (512 % 8 == 0)
  const int bid = (blockIdx.x & 7) * 64 + (blockIdx.x >> 3);
  const int bh = bid >> 4;            // 16 super-tiles per (b,h)
  const int qt = bid & 15;
  const int q0x = qt * 128 + wave * 16;
  const int q0y = q0x + 64;
  const size_t bhS = (size_t)bh * S_DIM;

  // staging coords (256 threads)
  const int key = tid >> 2;               // K: 0..63
  const int dq  = (tid & 3) << 4;         // K: d 0,16,32,48
  const int kp  = (tid & 31) << 1;        // V: even key 0..62
  const int dq8 = (tid >> 5) << 3;        // V: d octet 0..56

  // ---- Q fragments (B-operand): col=q=lane&15, k = kk*32 + g*8 + j ----
  short8 qfX[2], qfY[2];
  #pragma unroll
  for (int kk = 0; kk < 2; ++kk) {
    const float* sx = Qp + (bhS + (size_t)(q0x + c)) * D_DIM + kk*32 + g*8;
    float4 a = ((const float4*)sx)[0];
    float4 b = ((const float4*)sx)[1];
    union { unsigned u[4]; short8 s; } w;
    w.u[0] = pkbf(a.x, a.y); w.u[1] = pkbf(a.z, a.w);
    w.u[2] = pkbf(b.x, b.y); w.u[3] = pkbf(b.z, b.w);
    qfX[kk] = w.s;
    const float* sy = Qp + (bhS + (size_t)(q0y + c)) * D_DIM + kk*32 + g*8;
    float4 ay = ((const float4*)sy)[0];
    float4 by = ((const float4*)sy)[1];
    w.u[0] = pkbf(ay.x, ay.y); w.u[1] = pkbf(ay.z, ay.w);
    w.u[2] = pkbf(by.x, by.y); w.u[3] = pkbf(by.z, by.w);
    qfY[kk] = w.s;
  }

  const float rvSX = maskp[bhS + q0x + c] ? CL2E : 0.0f;
  const float rvSY = maskp[bhS + q0y + c] ? CL2E : 0.0f;

  // prefetch registers
  float4 kr0, kr1, kr2, kr3;
  float4 vA0, vA1, vB0, vB1;
  unsigned kmr;

  auto load_k = [&](int kt_) {
    const float* s = Kp + (bhS + (size_t)(kt_ * KB + key)) * D_DIM + dq;
    kr0 = ((const float4*)s)[0]; kr1 = ((const float4*)s)[1];
    kr2 = ((const float4*)s)[2]; kr3 = ((const float4*)s)[3];
    kmr = maskp[bhS + kt_ * KB + key] ? 0xFFFFFFFFu : 0u;
  };
  auto load_v = [&](int kt_) {
    const float* s0 = Vp + (bhS + (size_t)(kt_ * KB + kp)) * D_DIM + dq8;
    vA0 = ((const float4*)s0)[0]; vA1 = ((const float4*)s0)[1];
    vB0 = ((const float4*)(s0 + D_DIM))[0]; vB1 = ((const float4*)(s0 + D_DIM))[1];
  };
  // col-masked K staging: masked key rows stored as exact zeros -> sacc==0
  // -> p = exp2(0 + Lm) = 1/sum, exactly the reference's value.
  auto write_k = [&](int buf) {
    union { unsigned u[4]; short8 s; } w0, w1;
    w0.u[0] = pkbf(kr0.x, kr0.y) & kmr; w0.u[1] = pkbf(kr0.z, kr0.w) & kmr;
    w0.u[2] = pkbf(kr1.x, kr1.y) & kmr; w0.u[3] = pkbf(kr1.z, kr1.w) & kmr;
    w1.u[0] = pkbf(kr2.x, kr2.y) & kmr; w1.u[1] = pkbf(kr2.z, kr2.w) & kmr;
    w1.u[2] = pkbf(kr3.x, kr3.y) & kmr; w1.u[3] = pkbf(kr3.z, kr3.w) & kmr;
    const int sw = (key & 7) << 3;
    *(short8*)&sK[buf][key * 64 + (dq ^ sw)]       = w0.s;
    *(short8*)&sK[buf][key * 64 + ((dq + 8) ^ sw)] = w1.s;
  };
  auto write_v = [&](int buf) {
    float fa[8], fb[8];
    *(float4*)&fa[0] = vA0; *(float4*)&fa[4] = vA1;
    *(float4*)&fb[0] = vB0; *(float4*)&fb[4] = vB1;
    #pragma unroll
    for (int e = 0; e < 8; ++e) {
      const int d = dq8 + e;
      *(unsigned*)&sV[buf][d * KB + (kp ^ ((d & 7) << 3))] = pkbf(fa[e], fb[e]);
    }
  };

  unsigned short* const myP = sP[wave];
  const int rh  = lane >> 4;
  const int c16 = lane & 15;
  float* const abx = attn + (bhS + (size_t)q0x) * S_DIM;
  float* const aby = attn + (bhS + (size_t)q0y) * S_DIM;

  // attn copy-out from sP: 4 rows x 256B = 1KB contiguous per store
  auto copyout = [&](float* ab, int kt_) {
    float* const at = ab + kt_*KB;
    #pragma unroll
    for (int j = 0; j < 4; ++j) {
      const int rr = j*4 + rh;
      const int p8 = (c16 >> 1) ^ (rr & 7);
      uint2v u = *(const uint2v*)&myP[rr*64 + p8*8 + (c16 & 1)*4];
      union { unsigned iu; float f; } t0, t1, t2, t3;
      t0.iu = u.x << 16; t1.iu = u.x & 0xFFFF0000u;
      t2.iu = u.y << 16; t3.iu = u.y & 0xFFFF0000u;
      f32x4 o; o[0] = t0.f; o[1] = t1.f; o[2] = t2.f; o[3] = t3.f;
      __builtin_nontemporal_store(o, (f32x4*)(at + (size_t)rr * S_DIM + c16*4));
    }
  };

  auto read_kf = [&](int cur, short8 (&kf)[4][2]) {
    #pragma unroll
    for (int n = 0; n < 4; ++n) {
      const int k2 = n*16 + c;
      const int sw = (c & 7) << 3;
      #pragma unroll
      for (int kk = 0; kk < 2; ++kk)
        kf[n][kk] = *(const short8*)&sK[cur][k2*64 + ((kk*32 + g*8) ^ sw)];
    }
  };

  // ================= phase A: pass1(X) =================
  float lsumX = 0.0f;
  load_k(0);
  for (int kt = 0; kt < NT; ++kt) {
    const int cur = kt & 1;
    write_k(cur);
    if (kt + 1 < NT) load_k(kt + 1);
    else { load_k(0); load_v(0); }       // prefetch for phase B
    barrier_lds();

    short8 kf[4][2];
    read_kf(cur, kf);
    f32x4 sacc[4];
    #pragma unroll
    for (int n = 0; n < 4; ++n) sacc[n] = 0.0f;
    __builtin_amdgcn_s_setprio(1);
    #pragma unroll
    for (int n = 0; n < 4; ++n)
      #pragma unroll
      for (int kk = 0; kk < 2; ++kk)
        sacc[n] = __builtin_amdgcn_mfma_f32_16x16x32_bf16(kf[n][kk], qfX[kk], sacc[n], 0, 0, 0);
    __builtin_amdgcn_s_setprio(0);
    #pragma unroll
    for (int n = 0; n < 4; ++n)
      #pragma unroll
      for (int e = 0; e < 4; ++e)
        lsumX += fexp2(sacc[n][e] * rvSX);
  }
  float LmX;
  {
    float v = lsumX;
    v += __shfl_xor(v, 16);
    v += __shfl_xor(v, 32);
    LmX = -__log2f(v);
  }

  // ================= phase B: pass2(X) || pass1(Y) =================
  f32x4 oaccX[4];
  #pragma unroll
  for (int n = 0; n < 4; ++n) oaccX[n] = 0.0f;
  float lsumY = 0.0f;

  for (int kt = 0; kt < NT; ++kt) {
    const int cur = kt & 1;
    write_k(cur);
    write_v(cur);
    if (kt + 1 < NT) { load_k(kt + 1); load_v(kt + 1); }
    else { load_k(0); load_v(0); }       // prefetch for phase C
    barrier_lds();

    short8 kf[4][2];
    read_kf(cur, kf);                    // shared by X-recompute and Y-sum

    f32x4 saccX[4], saccY[4];
    #pragma unroll
    for (int n = 0; n < 4; ++n) { saccX[n] = 0.0f; saccY[n] = 0.0f; }
    __builtin_amdgcn_s_setprio(1);
    #pragma unroll
    for (int n = 0; n < 4; ++n)
      #pragma unroll
      for (int kk = 0; kk < 2; ++kk) {
        saccX[n] = __builtin_amdgcn_mfma_f32_16x16x32_bf16(kf[n][kk], qfX[kk], saccX[n], 0, 0, 0);
        saccY[n] = __builtin_amdgcn_mfma_f32_16x16x32_bf16(kf[n][kk], qfY[kk], saccY[n], 0, 0, 0);
      }
    __builtin_amdgcn_s_setprio(0);

    // X: p = exp2(s*rvS + Lm) -> bf16 into wave-private sP (swizzled)
    #pragma unroll
    for (int n = 0; n < 4; ++n) {
      f32x4 pv;
      #pragma unroll
      for (int e = 0; e < 4; ++e)
        pv[e] = fexp2(__builtin_fmaf(saccX[n][e], rvSX, LmX));
      const int swk = (n*16 + g*4) ^ ((c & 7) << 3);
      uint2v pr; pr.x = pkbf(pv[0], pv[1]); pr.y = pkbf(pv[2], pv[3]);
      *(uint2v*)&myP[c*64 + swk] = pr;
    }

    // Y: row-sum accumulation (independent VALU)
    #pragma unroll
    for (int n = 0; n < 4; ++n)
      #pragma unroll
      for (int e = 0; e < 4; ++e)
        lsumY += fexp2(saccY[n][e] * rvSY);

    // X: PV
    short8 pf[2];
    #pragma unroll
    for (int kk = 0; kk < 2; ++kk)
      pf[kk] = *(const short8*)&myP[c*64 + ((kk*32 + g*8) ^ ((c & 7) << 3))];
    __builtin_amdgcn_s_setprio(1);
    #pragma unroll
    for (int n = 0; n < 4; ++n) {
      const int d = n*16 + c;
      const int sw = (d & 7) << 3;
      #pragma unroll
      for (int kk = 0; kk < 2; ++kk) {
        short8 vf = *(const short8*)&sV[cur][d*KB + ((kk*32 + g*8) ^ sw)];
        oaccX[n] = __builtin_amdgcn_mfma_f32_16x16x32_bf16(pf[kk], vf, oaccX[n], 0, 0, 0);
      }
    }
    __builtin_amdgcn_s_setprio(0);

    copyout(abx, kt);
  }

  // ctx(X)
  #pragma unroll
  for (int n = 0; n < 4; ++n)
    #pragma unroll
    for (int e = 0; e < 4; ++e)
      ctx[(bhS + (size_t)(q0x + g*4 + e)) * D_DIM + (size_t)(n*16 + c)] = oaccX[n][e];

  float LmY;
  {
    float v = lsumY;
    v += __shfl_xor(v, 16);
    v += __shfl_xor(v, 32);
    LmY = -__log2f(v);
  }

  // ================= phase C: pass2(Y) =================
  f32x4 oaccY[4];
  #pragma unroll
  for (int n = 0; n < 4; ++n) oaccY[n] = 0.0f;

  for (int kt = 0; kt < NT; ++kt) {
    const int cur = kt & 1;
    write_k(cur);
    write_v(cur);
    if (kt + 1 < NT) { load_k(kt + 1); load_v(kt + 1); }
    barrier_lds();

    short8 kf[4][2];
    read_kf(cur, kf);
    f32x4 sacc[4];
    #pragma unroll
    for (int n = 0; n < 4; ++n) sacc[n] = 0.0f;
    __builtin_amdgcn_s_setprio(1);
    #pragma unroll
    for (int n = 0; n < 4; ++n)
      #pragma unroll
      for (int kk = 0; kk < 2; ++kk)
        sacc[n] = __builtin_amdgcn_mfma_f32_16x16x32_bf16(kf[n][kk], qfY[kk], sacc[n], 0, 0, 0);
    __builtin_amdgcn_s_setprio(0);

    #pragma unroll
    for (int n = 0; n < 4; ++n) {
      f32x4 pv;
      #pragma unroll
      for (int e = 0; e < 4; ++e)
        pv[e] = fexp2(__builtin_fmaf(sacc[n][e], rvSY, LmY));
      const int swk = (n*16 + g*4) ^ ((c & 7) << 3);
      uint2v pr; pr.x = pkbf(pv[0], pv[1]); pr.y = pkbf(pv[2], pv[3]);
      *(uint2v*)&myP[c*64 + swk] = pr;
    }

    short8 pf[2];
    #pragma unroll
    for (int kk = 0; kk < 2; ++kk)
      pf[kk] = *(const short8*)&myP[c*64 + ((kk*32 + g*8) ^ ((c & 7) << 3))];
    __builtin_amdgcn_s_setprio(1);
    #pragma unroll
    for (int n = 0; n < 4; ++n) {
      const int d = n*16 + c;
      const int sw = (d & 7) << 3;
      #pragma unroll
      for (int kk = 0; kk < 2; ++kk) {
        short8 vf = *(const short8*)&sV[cur][d*KB + ((kk*32 + g*8) ^ sw)];
        oaccY[n] = __builtin_amdgcn_mfma_f32_16x16x32_bf16(pf[kk], vf, oaccY[n], 0, 0, 0);
      }
    }
    __builtin_amdgcn_s_setprio(0);

    copyout(aby, kt);
  }

  // ctx(Y)
  #pragma unroll
  for (int n = 0; n < 4; ++n)
    #pragma unroll
    for (int e = 0; e < 4; ++e)
      ctx[(bhS + (size_t)(q0y + g*4 + e)) * D_DIM + (size_t)(n*16 + c)] = oaccY[n][e];
}

extern "C" void kernel_launch(void* const* d_in, const int* in_sizes, int n_in,
                              void* d_out, int out_size, void* d_ws, size_t ws_size,
                              hipStream_t stream) {
  const float* Q = (const float*)d_in[0];
  const float* K = (const float*)d_in[1];
  const float* V = (const float*)d_in[2];
  const int*   M = (const int*)d_in[3];
  float* ctx  = (float*)d_out;
  float* attn = ctx + (size_t)B_DIM * H_DIM * S_DIM * D_DIM;
  dim3 grid(B_DIM * H_DIM * (S_DIM / 128));   // 512 blocks of 256 threads
  sdpa_kernel<<<grid, 256, 0, stream>>>(Q, K, V, M, ctx, attn);
}

// Round 13
// 147.767 us; speedup vs baseline: 1.0621x; 1.0511x over previous
//
#include <hip/hip_runtime.h>

#define B_DIM 2
#define H_DIM 16
#define S_DIM 2048
#define D_DIM 64

constexpr int KB = 64;             // keys per tile
constexpr int NT = S_DIM / KB;     // 32 key tiles
constexpr float CL2E = 0.18033688011112042f;  // (1/sqrt(64)) * log2(e)

typedef __attribute__((ext_vector_type(8))) short short8;   // 8 bf16
typedef __attribute__((ext_vector_type(4))) float f32x4;
typedef __attribute__((ext_vector_type(2))) unsigned uint2v;

__device__ __forceinline__ unsigned pkbf(float lo, float hi) {
  unsigned r;
  asm("v_cvt_pk_bf16_f32 %0, %1, %2" : "=v"(r) : "v"(lo), "v"(hi));
  return r;
}

__device__ __forceinline__ float fexp2(float x) {
  float r;
  asm("v_exp_f32 %0, %1" : "=v"(r) : "v"(x));
  return r;
}

// drain LDS ops (cross-wave visibility) but NOT vmcnt — prefetch global
// loads stay in flight across the barrier (T14).
__device__ __forceinline__ void barrier_lds() {
  asm volatile("s_waitcnt lgkmcnt(0)" ::: "memory");
  __builtin_amdgcn_s_barrier();
  asm volatile("" ::: "memory");
}

// One block = 512 threads (8 waves) = one 256-row q-super-tile: X = rows
// [0,128), Y = rows [128,256); each wave owns 16 rows of X and 16 of Y.
// Phase A: pass1(X).  Phase B: pass2(X) fused with pass1(Y) per K-tile
// (shared staged K + shared kf fragments; X's stores drain under Y's
// compute).  Phase C: pass2(Y).  copyout is issued right after the
// P-write (before PV) so stores enter the queue earlier each tile.
__global__ __launch_bounds__(512, 2)
void sdpa_kernel(const float* __restrict__ Qp, const float* __restrict__ Kp,
                 const float* __restrict__ Vp, const int* __restrict__ maskp,
                 float* __restrict__ ctx, float* __restrict__ attn)
{
  __shared__ __align__(16) unsigned short sK[2][KB * 64];   // [buf][key][d] bf16, swizzled, col-masked
  __shared__ __align__(16) unsigned short sV[2][64 * KB];   // [buf][d][key] bf16, swizzled
  __shared__ __align__(16) unsigned short sP[8][16 * 64];   // per-wave P [q16][key] bf16, swizzled

  const int tid  = threadIdx.x;
  const int wave = tid >> 6;
  const int lane = tid & 63;
  const int c = lane & 15;      // fragment col (q within 16)
  const int g = lane >> 4;      // fragment key-subgroup

  // XCD-aware bijective swizzle (256 % 8 == 0)
  const int bid = (blockIdx.x & 7) * 32 + (blockIdx.x >> 3);
  const int bh = bid >> 3;            // 8 super-tiles per (b,h)
  const int qt = bid & 7;
  const int q0x = qt * 256 + wave * 16;
  const int q0y = q0x + 128;
  const size_t bhS = (size_t)bh * S_DIM;

  // staging coords (512 threads)
  const int keyk = tid >> 3;              // K: 0..63
  const int dqk  = (tid & 7) << 3;        // K: d octet 0..56
  const int kpv  = (tid & 31) << 1;       // V: even key 0..62
  const int d4   = (tid >> 5) << 2;       // V: d quad 0..60

  // ---- Q fragments (B-operand): col=q=lane&15, k = kk*32 + g*8 + j ----
  short8 qfX[2], qfY[2];
  #pragma unroll
  for (int kk = 0; kk < 2; ++kk) {
    const float* sx = Qp + (bhS + (size_t)(q0x + c)) * D_DIM + kk*32 + g*8;
    float4 a = ((const float4*)sx)[0];
    float4 b = ((const float4*)sx)[1];
    union { unsigned u[4]; short8 s; } w;
    w.u[0] = pkbf(a.x, a.y); w.u[1] = pkbf(a.z, a.w);
    w.u[2] = pkbf(b.x, b.y); w.u[3] = pkbf(b.z, b.w);
    qfX[kk] = w.s;
    const float* sy = Qp + (bhS + (size_t)(q0y + c)) * D_DIM + kk*32 + g*8;
    float4 ay = ((const float4*)sy)[0];
    float4 by = ((const float4*)sy)[1];
    w.u[0] = pkbf(ay.x, ay.y); w.u[1] = pkbf(ay.z, ay.w);
    w.u[2] = pkbf(by.x, by.y); w.u[3] = pkbf(by.z, by.w);
    qfY[kk] = w.s;
  }

  const float rvSX = maskp[bhS + q0x + c] ? CL2E : 0.0f;
  const float rvSY = maskp[bhS + q0y + c] ? CL2E : 0.0f;

  // prefetch registers
  float4 kA, kB;            // K: 8 floats
  float4 vA, vB;            // V: 2 keys x 4 d
  unsigned kmr;

  auto load_k = [&](int kt_) {
    const float* s = Kp + (bhS + (size_t)(kt_ * KB + keyk)) * D_DIM + dqk;
    kA = ((const float4*)s)[0]; kB = ((const float4*)s)[1];
    kmr = maskp[bhS + kt_ * KB + keyk] ? 0xFFFFFFFFu : 0u;
  };
  auto load_v = [&](int kt_) {
    const float* s0 = Vp + (bhS + (size_t)(kt_ * KB + kpv)) * D_DIM + d4;
    vA = *(const float4*)s0;
    vB = *(const float4*)(s0 + D_DIM);
  };
  // col-masked K staging: masked key rows stored as exact zeros -> sacc==0
  // -> p = exp2(0 + Lm) = 1/sum, exactly the reference's value.
  auto write_k = [&](int buf) {
    union { unsigned u[4]; short8 s; } w;
    w.u[0] = pkbf(kA.x, kA.y) & kmr; w.u[1] = pkbf(kA.z, kA.w) & kmr;
    w.u[2] = pkbf(kB.x, kB.y) & kmr; w.u[3] = pkbf(kB.z, kB.w) & kmr;
    *(short8*)&sK[buf][keyk * 64 + (dqk ^ ((keyk & 7) << 3))] = w.s;
  };
  auto write_v = [&](int buf) {
    float fa[4], fb[4];
    *(float4*)fa = vA; *(float4*)fb = vB;
    #pragma unroll
    for (int e = 0; e < 4; ++e) {
      const int d = d4 + e;
      *(unsigned*)&sV[buf][d * KB + (kpv ^ ((d & 7) << 3))] = pkbf(fa[e], fb[e]);
    }
  };

  unsigned short* const myP = sP[wave];
  const int rh  = lane >> 4;
  const int c16 = lane & 15;
  float* const abx = attn + (bhS + (size_t)q0x) * S_DIM;
  float* const aby = attn + (bhS + (size_t)q0y) * S_DIM;

  // attn copy-out from sP: 4 rows x 256B = 1KB contiguous per store
  auto copyout = [&](float* ab, int kt_) {
    float* const at = ab + kt_*KB;
    #pragma unroll
    for (int j = 0; j < 4; ++j) {
      const int rr = j*4 + rh;
      const int p8 = (c16 >> 1) ^ (rr & 7);
      uint2v u = *(const uint2v*)&myP[rr*64 + p8*8 + (c16 & 1)*4];
      union { unsigned iu; float f; } t0, t1, t2, t3;
      t0.iu = u.x << 16; t1.iu = u.x & 0xFFFF0000u;
      t2.iu = u.y << 16; t3.iu = u.y & 0xFFFF0000u;
      f32x4 o; o[0] = t0.f; o[1] = t1.f; o[2] = t2.f; o[3] = t3.f;
      __builtin_nontemporal_store(o, (f32x4*)(at + (size_t)rr * S_DIM + c16*4));
    }
  };

  auto read_kf = [&](int cur, short8 (&kf)[4][2]) {
    #pragma unroll
    for (int n = 0; n < 4; ++n) {
      const int k2 = n*16 + c;
      const int sw = (c & 7) << 3;
      #pragma unroll
      for (int kk = 0; kk < 2; ++kk)
        kf[n][kk] = *(const short8*)&sK[cur][k2*64 + ((kk*32 + g*8) ^ sw)];
    }
  };

  // ================= phase A: pass1(X) =================
  float lsumX = 0.0f;
  load_k(0);
  for (int kt = 0; kt < NT; ++kt) {
    const int cur = kt & 1;
    write_k(cur);
    if (kt + 1 < NT) load_k(kt + 1);
    else { load_k(0); load_v(0); }       // prefetch for phase B
    barrier_lds();

    short8 kf[4][2];
    read_kf(cur, kf);
    f32x4 sacc[4];
    #pragma unroll
    for (int n = 0; n < 4; ++n) sacc[n] = 0.0f;
    __builtin_amdgcn_s_setprio(1);
    #pragma unroll
    for (int n = 0; n < 4; ++n)
      #pragma unroll
      for (int kk = 0; kk < 2; ++kk)
        sacc[n] = __builtin_amdgcn_mfma_f32_16x16x32_bf16(kf[n][kk], qfX[kk], sacc[n], 0, 0, 0);
    __builtin_amdgcn_s_setprio(0);
    #pragma unroll
    for (int n = 0; n < 4; ++n)
      #pragma unroll
      for (int e = 0; e < 4; ++e)
        lsumX += fexp2(sacc[n][e] * rvSX);
  }
  float LmX;
  {
    float v = lsumX;
    v += __shfl_xor(v, 16);
    v += __shfl_xor(v, 32);
    LmX = -__log2f(v);
  }

  // ================= phase B: pass2(X) || pass1(Y) =================
  f32x4 oaccX[4];
  #pragma unroll
  for (int n = 0; n < 4; ++n) oaccX[n] = 0.0f;
  float lsumY = 0.0f;

  for (int kt = 0; kt < NT; ++kt) {
    const int cur = kt & 1;
    write_k(cur);
    write_v(cur);
    if (kt + 1 < NT) { load_k(kt + 1); load_v(kt + 1); }
    else { load_k(0); load_v(0); }       // prefetch for phase C
    barrier_lds();

    short8 kf[4][2];
    read_kf(cur, kf);                    // shared by X-recompute and Y-sum

    f32x4 saccX[4], saccY[4];
    #pragma unroll
    for (int n = 0; n < 4; ++n) { saccX[n] = 0.0f; saccY[n] = 0.0f; }
    __builtin_amdgcn_s_setprio(1);
    #pragma unroll
    for (int n = 0; n < 4; ++n)
      #pragma unroll
      for (int kk = 0; kk < 2; ++kk) {
        saccX[n] = __builtin_amdgcn_mfma_f32_16x16x32_bf16(kf[n][kk], qfX[kk], saccX[n], 0, 0, 0);
        saccY[n] = __builtin_amdgcn_mfma_f32_16x16x32_bf16(kf[n][kk], qfY[kk], saccY[n], 0, 0, 0);
      }
    __builtin_amdgcn_s_setprio(0);

    // X: p = exp2(s*rvS + Lm) -> bf16 into wave-private sP (swizzled)
    #pragma unroll
    for (int n = 0; n < 4; ++n) {
      f32x4 pv;
      #pragma unroll
      for (int e = 0; e < 4; ++e)
        pv[e] = fexp2(__builtin_fmaf(saccX[n][e], rvSX, LmX));
      const int swk = (n*16 + g*4) ^ ((c & 7) << 3);
      uint2v pr; pr.x = pkbf(pv[0], pv[1]); pr.y = pkbf(pv[2], pv[3]);
      *(uint2v*)&myP[c*64 + swk] = pr;
    }

    // stores issue as early as possible; they drain under Y-sum + PV
    copyout(abx, kt);

    // Y: row-sum accumulation (independent VALU)
    #pragma unroll
    for (int n = 0; n < 4; ++n)
      #pragma unroll
      for (int e = 0; e < 4; ++e)
        lsumY += fexp2(saccY[n][e] * rvSY);

    // X: PV
    short8 pf[2];
    #pragma unroll
    for (int kk = 0; kk < 2; ++kk)
      pf[kk] = *(const short8*)&myP[c*64 + ((kk*32 + g*8) ^ ((c & 7) << 3))];
    __builtin_amdgcn_s_setprio(1);
    #pragma unroll
    for (int n = 0; n < 4; ++n) {
      const int d = n*16 + c;
      const int sw = (d & 7) << 3;
      #pragma unroll
      for (int kk = 0; kk < 2; ++kk) {
        short8 vf = *(const short8*)&sV[cur][d*KB + ((kk*32 + g*8) ^ sw)];
        oaccX[n] = __builtin_amdgcn_mfma_f32_16x16x32_bf16(pf[kk], vf, oaccX[n], 0, 0, 0);
      }
    }
    __builtin_amdgcn_s_setprio(0);
  }

  // ctx(X)
  #pragma unroll
  for (int n = 0; n < 4; ++n)
    #pragma unroll
    for (int e = 0; e < 4; ++e)
      ctx[(bhS + (size_t)(q0x + g*4 + e)) * D_DIM + (size_t)(n*16 + c)] = oaccX[n][e];

  float LmY;
  {
    float v = lsumY;
    v += __shfl_xor(v, 16);
    v += __shfl_xor(v, 32);
    LmY = -__log2f(v);
  }

  // ================= phase C: pass2(Y) =================
  f32x4 oaccY[4];
  #pragma unroll
  for (int n = 0; n < 4; ++n) oaccY[n] = 0.0f;

  for (int kt = 0; kt < NT; ++kt) {
    const int cur = kt & 1;
    write_k(cur);
    write_v(cur);
    if (kt + 1 < NT) { load_k(kt + 1); load_v(kt + 1); }
    barrier_lds();

    short8 kf[4][2];
    read_kf(cur, kf);
    f32x4 sacc[4];
    #pragma unroll
    for (int n = 0; n < 4; ++n) sacc[n] = 0.0f;
    __builtin_amdgcn_s_setprio(1);
    #pragma unroll
    for (int n = 0; n < 4; ++n)
      #pragma unroll
      for (int kk = 0; kk < 2; ++kk)
        sacc[n] = __builtin_amdgcn_mfma_f32_16x16x32_bf16(kf[n][kk], qfY[kk], sacc[n], 0, 0, 0);
    __builtin_amdgcn_s_setprio(0);

    #pragma unroll
    for (int n = 0; n < 4; ++n) {
      f32x4 pv;
      #pragma unroll
      for (int e = 0; e < 4; ++e)
        pv[e] = fexp2(__builtin_fmaf(sacc[n][e], rvSY, LmY));
      const int swk = (n*16 + g*4) ^ ((c & 7) << 3);
      uint2v pr; pr.x = pkbf(pv[0], pv[1]); pr.y = pkbf(pv[2], pv[3]);
      *(uint2v*)&myP[c*64 + swk] = pr;
    }

    // stores issue before PV
    copyout(aby, kt);

    short8 pf[2];
    #pragma unroll
    for (int kk = 0; kk < 2; ++kk)
      pf[kk] = *(const short8*)&myP[c*64 + ((kk*32 + g*8) ^ ((c & 7) << 3))];
    __builtin_amdgcn_s_setprio(1);
    #pragma unroll
    for (int n = 0; n < 4; ++n) {
      const int d = n*16 + c;
      const int sw = (d & 7) << 3;
      #pragma unroll
      for (int kk = 0; kk < 2; ++kk) {
        short8 vf = *(const short8*)&sV[cur][d*KB + ((kk*32 + g*8) ^ sw)];
        oaccY[n] = __builtin_amdgcn_mfma_f32_16x16x32_bf16(pf[kk], vf, oaccY[n], 0, 0, 0);
      }
    }
    __builtin_amdgcn_s_setprio(0);
  }

  // ctx(Y)
  #pragma unroll
  for (int n = 0; n < 4; ++n)
    #pragma unroll
    for (int e = 0; e < 4; ++e)
      ctx[(bhS + (size_t)(q0y + g*4 + e)) * D_DIM + (size_t)(n*16 + c)] = oaccY[n][e];
}

extern "C" void kernel_launch(void* const* d_in, const int* in_sizes, int n_in,
                              void* d_out, int out_size, void* d_ws, size_t ws_size,
                              hipStream_t stream) {
  const float* Q = (const float*)d_in[0];
  const float* K = (const float*)d_in[1];
  const float* V = (const float*)d_in[2];
  const int*   M = (const int*)d_in[3];
  float* ctx  = (float*)d_out;
  float* attn = ctx + (size_t)B_DIM * H_DIM * S_DIM * D_DIM;
  dim3 grid(B_DIM * H_DIM * (S_DIM / 256));   // 256 blocks of 512 threads
  sdpa_kernel<<<grid, 512, 0, stream>>>(Q, K, V, M, ctx, attn);
}